// Round 1
// baseline (302.781 us; speedup 1.0000x reference)
//
#include <hip/hip_runtime.h>
#include <math.h>

#define EMBED 1024
#define NHEAD 16
#define HDIM  64
#define CLEN  16384

// ---- workspace layout (float offsets) ----
// qkv: q[1024] | k_i[1024] | v_i[1024]
#define WS_QKV   0
#define WS_PM    3072                 // per-wave max   [1024*16]
#define WS_PL    19456                // per-wave l     [1024*16]
#define WS_PACC  35840                // per-wave acc   [1024*1024]
#define WS_GM    1084416              // per-group max  [32*16]
#define WS_GL    1084928              // per-group l    [32*16]
#define WS_GACC  1085440              // per-group acc  [32*1024]
#define WS_VALS  1118208              // values [1024]
// total = 1119232 floats ~= 4.48 MB

// ---------------------------------------------------------------------------
// Kernel A: q/k/v projections.  96 blocks = 3 matrices x 32 i-chunks of 32
// rows; each thread owns 4 consecutive output columns (float4 coalesced W
// reads); partial sums land via atomicAdd in pre-zeroed ws.  Bias added by
// the i-chunk-0 block.
// ---------------------------------------------------------------------------
__global__ __launch_bounds__(256) void qkv_proj(
    const float* __restrict__ x,
    const float* __restrict__ Wq, const float* __restrict__ bq,
    const float* __restrict__ Wk, const float* __restrict__ bk,
    const float* __restrict__ Wv, const float* __restrict__ bv,
    float* __restrict__ ws) {
  int m  = blockIdx.x >> 5;            // 0:q 1:k 2:v
  int i0 = (blockIdx.x & 31) * 32;
  const float* W; const float* b;
  if (m == 0)      { W = Wq; b = bq; }
  else if (m == 1) { W = Wk; b = bk; }
  else             { W = Wv; b = bv; }
  int j = threadIdx.x << 2;
  float4 acc = make_float4(0.f, 0.f, 0.f, 0.f);
  if (i0 == 0) acc = *(const float4*)(b + j);
  for (int i = i0; i < i0 + 32; ++i) {
    float xv = x[i];
    float4 w = *(const float4*)(W + (size_t)i * EMBED + j);
    acc.x += xv * w.x; acc.y += xv * w.y;
    acc.z += xv * w.z; acc.w += xv * w.w;
  }
  float* dst = ws + WS_QKV + (size_t)m * EMBED + j;
  atomicAdd(dst + 0, acc.x); atomicAdd(dst + 1, acc.y);
  atomicAdd(dst + 2, acc.z); atomicAdd(dst + 3, acc.w);
}

// ---------------------------------------------------------------------------
// Kernel B: fused cache-shift + online-softmax attention.
// 256 blocks x 256 threads = 1024 waves; wave w owns positions [16w, 16w+16).
// Lane layout: head h = lane/4, dims d = (lane%4)*16 .. +15 (16 floats/lane).
// For each position: float4 copy v,k (src = t+1, or new token for t=16383),
// per-head dot via 2-step __shfl_xor, wave-wide __any for the mask, online
// m/l/acc update with v already in registers.  Partials -> ws.
// ---------------------------------------------------------------------------
__global__ __launch_bounds__(256) void shift_attn(
    const float* __restrict__ cache,   // (2, 16384, 1024): v then k
    float* __restrict__ out,           // d_out
    float* __restrict__ ws) {
  const int wave = ((blockIdx.x << 8) + threadIdx.x) >> 6;  // 0..1023
  const int lane = threadIdx.x & 63;
  const int h    = lane >> 2;
  const int e    = h * HDIM + ((lane & 3) << 4);   // element offset in [0,1024)

  float qf[16];
#pragma unroll
  for (int j = 0; j < 16; j += 4) {
    float4 t = *(const float4*)(ws + WS_QKV + e + j);
    qf[j] = t.x; qf[j + 1] = t.y; qf[j + 2] = t.z; qf[j + 3] = t.w;
  }

  float mrun = -INFINITY, lsum = 0.f;
  float acc[16];
#pragma unroll
  for (int j = 0; j < 16; ++j) acc[j] = 0.f;

  const float* vin  = cache;
  const float* kin  = cache + (size_t)CLEN * EMBED;
  float* vout = out + EMBED;
  float* kout = out + EMBED + (size_t)CLEN * EMBED;
  const int t0 = wave * 16;

  for (int it = 0; it < 16; ++it) {
    int t = t0 + it;
    const float* vsrc = (t < CLEN - 1) ? (vin + (size_t)(t + 1) * EMBED + e)
                                       : (ws + WS_QKV + 2 * EMBED + e);
    const float* ksrc = (t < CLEN - 1) ? (kin + (size_t)(t + 1) * EMBED + e)
                                       : (ws + WS_QKV + EMBED + e);
    float vv[16], kk[16];
#pragma unroll
    for (int j = 0; j < 16; j += 4) {
      float4 tv = *(const float4*)(vsrc + j);
      vv[j] = tv.x; vv[j + 1] = tv.y; vv[j + 2] = tv.z; vv[j + 3] = tv.w;
    }
#pragma unroll
    for (int j = 0; j < 16; j += 4) {
      float4 tk = *(const float4*)(ksrc + j);
      kk[j] = tk.x; kk[j + 1] = tk.y; kk[j + 2] = tk.z; kk[j + 3] = tk.w;
    }
    float* vd = vout + (size_t)t * EMBED + e;
    float* kd = kout + (size_t)t * EMBED + e;
#pragma unroll
    for (int j = 0; j < 16; j += 4)
      *(float4*)(vd + j) = make_float4(vv[j], vv[j + 1], vv[j + 2], vv[j + 3]);
#pragma unroll
    for (int j = 0; j < 16; j += 4)
      *(float4*)(kd + j) = make_float4(kk[j], kk[j + 1], kk[j + 2], kk[j + 3]);

    bool nz = false;
#pragma unroll
    for (int j = 0; j < 16; ++j) nz = nz || (vv[j] != 0.f);
    float dot = 0.f;
#pragma unroll
    for (int j = 0; j < 16; ++j) dot += qf[j] * kk[j];
    dot += __shfl_xor(dot, 1, 64);
    dot += __shfl_xor(dot, 2, 64);

    if (__any((int)nz)) {
      float s  = dot * 0.125f;                 // 1/sqrt(64)
      float mn = fmaxf(mrun, s);
      float alpha = __expf(mrun - mn);         // exp(-inf)=0 on first hit
      float p     = __expf(s - mn);
      lsum = lsum * alpha + p;
#pragma unroll
      for (int j = 0; j < 16; ++j) acc[j] = acc[j] * alpha + p * vv[j];
      mrun = mn;
    }
  }

  if ((lane & 3) == 0) {
    ws[WS_PM + wave * NHEAD + h] = mrun;
    ws[WS_PL + wave * NHEAD + h] = lsum;
  }
  float* pa = ws + WS_PACC + (size_t)wave * EMBED + e;
#pragma unroll
  for (int j = 0; j < 16; j += 4)
    *(float4*)(pa + j) = make_float4(acc[j], acc[j + 1], acc[j + 2], acc[j + 3]);
}

// ---------------------------------------------------------------------------
// Kernel C1: combine 1024 wave-partials -> 32 group-partials.
// ---------------------------------------------------------------------------
__global__ __launch_bounds__(1024) void combine1(float* __restrict__ ws) {
  int g = blockIdx.x;            // 0..31, each combines 32 waves
  int tid = threadIdx.x;         // (h,d) flat
  int h = tid >> 6;
  int w0 = g * 32;
  float M = -INFINITY;
  for (int w = w0; w < w0 + 32; ++w)
    M = fmaxf(M, ws[WS_PM + w * NHEAD + h]);
  float L = 0.f, a = 0.f;
  for (int w = w0; w < w0 + 32; ++w) {
    float sc = __expf(ws[WS_PM + w * NHEAD + h] - M);
    L += sc * ws[WS_PL + w * NHEAD + h];
    a += sc * ws[WS_PACC + (size_t)w * EMBED + tid];
  }
  if ((tid & 63) == 0) {
    ws[WS_GM + g * NHEAD + h] = M;
    ws[WS_GL + g * NHEAD + h] = L;
  }
  ws[WS_GACC + (size_t)g * EMBED + tid] = a;
}

// ---------------------------------------------------------------------------
// Kernel C2: combine 32 group-partials -> final values[1024].
// ---------------------------------------------------------------------------
__global__ __launch_bounds__(1024) void combine2(float* __restrict__ ws) {
  int tid = threadIdx.x;
  int h = tid >> 6;
  float M = -INFINITY;
  for (int g = 0; g < 32; ++g)
    M = fmaxf(M, ws[WS_GM + g * NHEAD + h]);
  float L = 0.f, a = 0.f;
  for (int g = 0; g < 32; ++g) {
    float sc = __expf(ws[WS_GM + g * NHEAD + h] - M);
    L += sc * ws[WS_GL + g * NHEAD + h];
    a += sc * ws[WS_GACC + (size_t)g * EMBED + tid];
  }
  ws[WS_VALS + tid] = a / L;
}

// ---------------------------------------------------------------------------
// Kernel D: output projection out_i = values @ Wo + bo (atomics into
// pre-zeroed d_out[0:1024]).
// ---------------------------------------------------------------------------
__global__ __launch_bounds__(256) void out_proj(
    const float* __restrict__ ws,
    const float* __restrict__ Wo, const float* __restrict__ bo,
    float* __restrict__ out) {
  int i0 = blockIdx.x * 32;
  int j = threadIdx.x << 2;
  float4 acc = make_float4(0.f, 0.f, 0.f, 0.f);
  if (i0 == 0) acc = *(const float4*)(bo + j);
  const float* vals = ws + WS_VALS;
  for (int i = i0; i < i0 + 32; ++i) {
    float xv = vals[i];
    float4 w = *(const float4*)(Wo + (size_t)i * EMBED + j);
    acc.x += xv * w.x; acc.y += xv * w.y;
    acc.z += xv * w.z; acc.w += xv * w.w;
  }
  atomicAdd(out + j + 0, acc.x); atomicAdd(out + j + 1, acc.y);
  atomicAdd(out + j + 2, acc.z); atomicAdd(out + j + 3, acc.w);
}

extern "C" void kernel_launch(void* const* d_in, const int* in_sizes, int n_in,
                              void* d_out, int out_size, void* d_ws, size_t ws_size,
                              hipStream_t stream) {
  const float* x     = (const float*)d_in[0];
  const float* cache = (const float*)d_in[1];
  const float* Wv    = (const float*)d_in[2];
  const float* bv    = (const float*)d_in[3];
  const float* Wq    = (const float*)d_in[4];
  const float* bq    = (const float*)d_in[5];
  const float* Wk    = (const float*)d_in[6];
  const float* bk    = (const float*)d_in[7];
  const float* Wo    = (const float*)d_in[8];
  const float* bo    = (const float*)d_in[9];
  float* out = (float*)d_out;
  float* ws  = (float*)d_ws;

  // zero the atomic-accumulated regions (ws/d_out are poisoned 0xAA)
  hipMemsetAsync(ws, 0, 3 * EMBED * sizeof(float), stream);
  hipMemsetAsync(out, 0, EMBED * sizeof(float), stream);

  qkv_proj  <<<96, 256, 0, stream>>>(x, Wq, bq, Wk, bk, Wv, bv, ws);
  shift_attn<<<256, 256, 0, stream>>>(cache, out, ws);
  combine1  <<<32, 1024, 0, stream>>>(ws);
  combine2  <<<1, 1024, 0, stream>>>(ws);
  out_proj  <<<32, 256, 0, stream>>>(ws, Wo, bo, out);
}

// Round 2
// 297.571 us; speedup vs baseline: 1.0175x; 1.0175x over previous
//
#include <hip/hip_runtime.h>
#include <math.h>

#define EMBED 1024
#define NHEAD 16
#define HDIM  64
#define CLEN  16384

// ---- workspace layout (float offsets) ----
#define WS_QKV   0          // q[1024] | k_i[1024] | v_i[1024]
#define WS_QP    3072       // qkv split-K partials [3*64*1024]
#define WS_PM    199680     // block-partial m   [1024*16]
#define WS_PL    216064     // block-partial l   [1024*16]
#define WS_PACC  232448     // block-partial acc [1024*1024]
#define WS_GM    1281024    // group m   [32*16]
#define WS_GL    1281536    // group l   [32*16]
#define WS_GACC  1282048    // group acc [32*1024]
#define WS_VALS  1314816    // values [1024]
#define WS_OPART 1315840    // out-proj partials [64*1024]
// total = 1381376 floats ~= 5.5 MB

// ---------------------------------------------------------------------------
// A: q/k/v projection split-K partials. 192 blocks = 3 matrices x 64 K-chunks
// of 16 rows; thread owns 4 consecutive columns (float4). NO atomics.
// ---------------------------------------------------------------------------
__global__ __launch_bounds__(256) void qkv_proj(
    const float* __restrict__ x,
    const float* __restrict__ Wq,
    const float* __restrict__ Wk,
    const float* __restrict__ Wv,
    float* __restrict__ ws) {
  int m = blockIdx.x >> 6;             // 0:q 1:k 2:v
  int c = blockIdx.x & 63;             // K-chunk
  const float* W = (m == 0) ? Wq : (m == 1) ? Wk : Wv;
  int j = threadIdx.x << 2;
  int i0 = c * 16;
  float4 acc = make_float4(0.f, 0.f, 0.f, 0.f);
  for (int i = i0; i < i0 + 16; ++i) {
    float xv = x[i];
    float4 w = *(const float4*)(W + (size_t)i * EMBED + j);
    acc.x += xv * w.x; acc.y += xv * w.y;
    acc.z += xv * w.z; acc.w += xv * w.w;
  }
  *(float4*)(ws + WS_QP + (size_t)(m * 64 + c) * EMBED + j) = acc;
}

// A2: reduce 64 partials + bias -> q/k/v. 12 blocks x 256.
__global__ __launch_bounds__(256) void qkv_reduce(
    const float* __restrict__ bq, const float* __restrict__ bk,
    const float* __restrict__ bv, float* __restrict__ ws) {
  int m = blockIdx.x >> 2;
  int j = ((blockIdx.x & 3) << 8) + threadIdx.x;
  const float* b = (m == 0) ? bq : (m == 1) ? bk : bv;
  float s = b[j];
  const float* p = ws + WS_QP + (size_t)m * 64 * EMBED + j;
  for (int c = 0; c < 64; ++c) s += p[(size_t)c * EMBED];
  ws[WS_QKV + m * EMBED + j] = s;
}

// ---------------------------------------------------------------------------
// B: fused cache-shift + online-softmax attention.
// 1024 blocks x 256 threads = 4096 waves; wave handles 4 positions.
// Lane layout: head h = lane/4, 16 dims/lane. Intra-block LDS combine of the
// 4 wave-partials -> one block-partial (m,l,acc) in ws.
// ---------------------------------------------------------------------------
__global__ __launch_bounds__(256) void shift_attn(
    const float* __restrict__ cache,   // (2, 16384, 1024): v then k
    float* __restrict__ out,           // d_out
    float* __restrict__ ws) {
  __shared__ float sacc[4][EMBED];
  __shared__ float sm[4][NHEAD];
  __shared__ float sl[4][NHEAD];

  const int wv   = threadIdx.x >> 6;               // wave in block 0..3
  const int lane = threadIdx.x & 63;
  const int h    = lane >> 2;
  const int e    = h * HDIM + ((lane & 3) << 4);   // element offset [0,1024)

  float qf[16];
#pragma unroll
  for (int j = 0; j < 16; j += 4) {
    float4 t = *(const float4*)(ws + WS_QKV + e + j);
    qf[j] = t.x; qf[j + 1] = t.y; qf[j + 2] = t.z; qf[j + 3] = t.w;
  }

  float mrun = -INFINITY, lsum = 0.f;
  float acc[16];
#pragma unroll
  for (int j = 0; j < 16; ++j) acc[j] = 0.f;

  const float* vin = cache;
  const float* kin = cache + (size_t)CLEN * EMBED;
  float* vout = out + EMBED;
  float* kout = out + EMBED + (size_t)CLEN * EMBED;
  const int t0 = blockIdx.x * 16 + wv * 4;

  for (int it = 0; it < 4; ++it) {
    int t = t0 + it;
    const float* vsrc = (t < CLEN - 1) ? (vin + (size_t)(t + 1) * EMBED + e)
                                       : (ws + WS_QKV + 2 * EMBED + e);
    const float* ksrc = (t < CLEN - 1) ? (kin + (size_t)(t + 1) * EMBED + e)
                                       : (ws + WS_QKV + EMBED + e);
    float vv[16], kk[16];
#pragma unroll
    for (int j = 0; j < 16; j += 4) {
      float4 tv = *(const float4*)(vsrc + j);
      vv[j] = tv.x; vv[j + 1] = tv.y; vv[j + 2] = tv.z; vv[j + 3] = tv.w;
    }
#pragma unroll
    for (int j = 0; j < 16; j += 4) {
      float4 tk = *(const float4*)(ksrc + j);
      kk[j] = tk.x; kk[j + 1] = tk.y; kk[j + 2] = tk.z; kk[j + 3] = tk.w;
    }
    float* vd = vout + (size_t)t * EMBED + e;
    float* kd = kout + (size_t)t * EMBED + e;
#pragma unroll
    for (int j = 0; j < 16; j += 4)
      *(float4*)(vd + j) = make_float4(vv[j], vv[j + 1], vv[j + 2], vv[j + 3]);
#pragma unroll
    for (int j = 0; j < 16; j += 4)
      *(float4*)(kd + j) = make_float4(kk[j], kk[j + 1], kk[j + 2], kk[j + 3]);

    bool nz = false;
#pragma unroll
    for (int j = 0; j < 16; ++j) nz = nz || (vv[j] != 0.f);
    float dot = 0.f;
#pragma unroll
    for (int j = 0; j < 16; ++j) dot += qf[j] * kk[j];
    dot += __shfl_xor(dot, 1, 64);
    dot += __shfl_xor(dot, 2, 64);

    if (__any((int)nz)) {
      float s  = dot * 0.125f;                 // 1/sqrt(64)
      float mn = fmaxf(mrun, s);
      float alpha = __expf(mrun - mn);         // exp(-inf)=0 on first hit
      float p     = __expf(s - mn);
      lsum = lsum * alpha + p;
#pragma unroll
      for (int j = 0; j < 16; ++j) acc[j] = acc[j] * alpha + p * vv[j];
      mrun = mn;
    }
  }

  // intra-block combine: waves 1..3 park partials in LDS, wave 0 merges.
  if (wv > 0) {
#pragma unroll
    for (int j = 0; j < 16; j += 4)
      *(float4*)(&sacc[wv][e + j]) =
          make_float4(acc[j], acc[j + 1], acc[j + 2], acc[j + 3]);
    if ((lane & 3) == 0) { sm[wv][h] = mrun; sl[wv][h] = lsum; }
  }
  __syncthreads();
  if (wv == 0) {
    for (int w = 1; w < 4; ++w) {
      float m2 = sm[w][h];
      float M  = fmaxf(mrun, m2);
      float a1 = (mrun == -INFINITY) ? 0.f : __expf(mrun - M);
      float a2 = (m2   == -INFINITY) ? 0.f : __expf(m2 - M);
      lsum = a1 * lsum + a2 * sl[w][h];
#pragma unroll
      for (int j = 0; j < 16; j += 4) {
        float4 av = *(const float4*)(&sacc[w][e + j]);
        acc[j]     = a1 * acc[j]     + a2 * av.x;
        acc[j + 1] = a1 * acc[j + 1] + a2 * av.y;
        acc[j + 2] = a1 * acc[j + 2] + a2 * av.z;
        acc[j + 3] = a1 * acc[j + 3] + a2 * av.w;
      }
      mrun = M;
    }
    if ((lane & 3) == 0) {
      ws[WS_PM + blockIdx.x * NHEAD + h] = mrun;
      ws[WS_PL + blockIdx.x * NHEAD + h] = lsum;
    }
    float* pa = ws + WS_PACC + (size_t)blockIdx.x * EMBED + e;
#pragma unroll
    for (int j = 0; j < 16; j += 4)
      *(float4*)(pa + j) =
          make_float4(acc[j], acc[j + 1], acc[j + 2], acc[j + 3]);
  }
}

// C1: 1024 block-partials -> 32 group-partials. 32 blocks x 1024.
__global__ __launch_bounds__(1024) void combine1(float* __restrict__ ws) {
  int g = blockIdx.x, t = threadIdx.x, h = t >> 6;
  int w0 = g * 32;
  float M = -INFINITY;
  for (int w = w0; w < w0 + 32; ++w)
    M = fmaxf(M, ws[WS_PM + w * NHEAD + h]);
  float L = 0.f, a = 0.f;
  for (int w = w0; w < w0 + 32; ++w) {
    float mw = ws[WS_PM + w * NHEAD + h];
    float sc = (mw == -INFINITY) ? 0.f : __expf(mw - M);
    L += sc * ws[WS_PL + w * NHEAD + h];
    a += sc * ws[WS_PACC + (size_t)w * EMBED + t];
  }
  if ((t & 63) == 0) {
    ws[WS_GM + g * NHEAD + h] = M;
    ws[WS_GL + g * NHEAD + h] = L;
  }
  ws[WS_GACC + (size_t)g * EMBED + t] = a;
}

// C2: 32 group-partials -> values[1024]. 1 block x 1024.
__global__ __launch_bounds__(1024) void combine2(float* __restrict__ ws) {
  int t = threadIdx.x, h = t >> 6;
  float M = -INFINITY;
  for (int g = 0; g < 32; ++g)
    M = fmaxf(M, ws[WS_GM + g * NHEAD + h]);
  float L = 0.f, a = 0.f;
  for (int g = 0; g < 32; ++g) {
    float mg = ws[WS_GM + g * NHEAD + h];
    float sc = (mg == -INFINITY) ? 0.f : __expf(mg - M);
    L += sc * ws[WS_GL + g * NHEAD + h];
    a += sc * ws[WS_GACC + (size_t)g * EMBED + t];
  }
  ws[WS_VALS + t] = a / L;
}

// D: out-proj split-K partials. 64 blocks x 256 (16 rows each). NO atomics.
__global__ __launch_bounds__(256) void out_proj(
    const float* __restrict__ ws_in,
    const float* __restrict__ Wo,
    float* __restrict__ ws) {
  int c = blockIdx.x;
  int j = threadIdx.x << 2;
  int i0 = c * 16;
  const float* vals = ws_in + WS_VALS;
  float4 acc = make_float4(0.f, 0.f, 0.f, 0.f);
  for (int i = i0; i < i0 + 16; ++i) {
    float xv = vals[i];
    float4 w = *(const float4*)(Wo + (size_t)i * EMBED + j);
    acc.x += xv * w.x; acc.y += xv * w.y;
    acc.z += xv * w.z; acc.w += xv * w.w;
  }
  *(float4*)(ws + WS_OPART + (size_t)c * EMBED + j) = acc;
}

// D2: reduce 64 partials + bo -> d_out[0:1024]. 1 block x 1024.
__global__ __launch_bounds__(1024) void out_reduce(
    const float* __restrict__ ws, const float* __restrict__ bo,
    float* __restrict__ out) {
  int t = threadIdx.x;
  float s = bo[t];
  const float* p = ws + WS_OPART + t;
  for (int c = 0; c < 64; ++c) s += p[(size_t)c * EMBED];
  out[t] = s;
}

extern "C" void kernel_launch(void* const* d_in, const int* in_sizes, int n_in,
                              void* d_out, int out_size, void* d_ws, size_t ws_size,
                              hipStream_t stream) {
  const float* x     = (const float*)d_in[0];
  const float* cache = (const float*)d_in[1];
  const float* Wv    = (const float*)d_in[2];
  const float* bv    = (const float*)d_in[3];
  const float* Wq    = (const float*)d_in[4];
  const float* bq    = (const float*)d_in[5];
  const float* Wk    = (const float*)d_in[6];
  const float* bk    = (const float*)d_in[7];
  const float* Wo    = (const float*)d_in[8];
  const float* bo    = (const float*)d_in[9];
  float* out = (float*)d_out;
  float* ws  = (float*)d_ws;

  qkv_proj  <<<192, 256, 0, stream>>>(x, Wq, Wk, Wv, ws);
  qkv_reduce<<<12, 256, 0, stream>>>(bq, bk, bv, ws);
  shift_attn<<<1024, 256, 0, stream>>>(cache, out, ws);
  combine1  <<<32, 1024, 0, stream>>>(ws);
  combine2  <<<1, 1024, 0, stream>>>(ws);
  out_proj  <<<64, 256, 0, stream>>>(ws, Wo, ws);
  out_reduce<<<1, 1024, 0, stream>>>(ws, bo, out);
}

// Round 3
// 291.200 us; speedup vs baseline: 1.0398x; 1.0219x over previous
//
#include <hip/hip_runtime.h>
#include <math.h>

#define EMBED 1024
#define NHEAD 16
#define HDIM  64
#define CLEN  16384

// ---- workspace layout (float offsets) ----
#define WS_QKV   0          // q[1024] | k_i[1024] | v_i[1024]
#define WS_QP    3072       // qkv split-K partials [3*64*1024]
#define WS_PM    199680     // block-partial m   [1024*16]
#define WS_PL    216064     // block-partial l   [1024*16]
#define WS_PACC  232448     // block-partial acc [1024*1024]
#define WS_GM    1281024    // group m   [32*16]
#define WS_GL    1281536    // group l   [32*16]
#define WS_GACC  1282048    // group acc [32*1024]
#define WS_OPART 1314816    // out-proj partials [64*1024]
// total = 1380352 floats ~= 5.52 MB

// ---------------------------------------------------------------------------
// A: q/k/v projection split-K partials. 192 blocks = 3 matrices x 64 K-chunks
// of 16 rows; thread owns 4 consecutive columns (float4). NO atomics.
// ---------------------------------------------------------------------------
__global__ __launch_bounds__(256) void qkv_proj(
    const float* __restrict__ x,
    const float* __restrict__ Wq,
    const float* __restrict__ Wk,
    const float* __restrict__ Wv,
    float* __restrict__ ws) {
  int m = blockIdx.x >> 6;             // 0:q 1:k 2:v
  int c = blockIdx.x & 63;             // K-chunk
  const float* W = (m == 0) ? Wq : (m == 1) ? Wk : Wv;
  int j = threadIdx.x << 2;
  int i0 = c * 16;
  float4 acc = make_float4(0.f, 0.f, 0.f, 0.f);
  for (int i = i0; i < i0 + 16; ++i) {
    float xv = x[i];
    float4 w = *(const float4*)(W + (size_t)i * EMBED + j);
    acc.x += xv * w.x; acc.y += xv * w.y;
    acc.z += xv * w.z; acc.w += xv * w.w;
  }
  *(float4*)(ws + WS_QP + (size_t)(m * 64 + c) * EMBED + j) = acc;
}

// A2: reduce 64 partials + bias -> q/k/v. 12 blocks x 256.
__global__ __launch_bounds__(256) void qkv_reduce(
    const float* __restrict__ bq, const float* __restrict__ bk,
    const float* __restrict__ bv, float* __restrict__ ws) {
  int m = blockIdx.x >> 2;
  int j = ((blockIdx.x & 3) << 8) + threadIdx.x;
  const float* b = (m == 0) ? bq : (m == 1) ? bk : bv;
  float s = b[j];
  const float* p = ws + WS_QP + (size_t)m * 64 * EMBED + j;
  for (int c = 0; c < 64; ++c) s += p[(size_t)c * EMBED];
  ws[WS_QKV + m * EMBED + j] = s;
}

// ---------------------------------------------------------------------------
// B: fused cache-shift + online-softmax attention, COALESCED layout.
// 1024 blocks x 256 threads; wave wv handles positions t0..t0+3 alone:
// lane i owns elements {c*256 + i*4 .. +3} for chunks c=0..3, so every
// float4 load/store is a fully-coalesced 1 KB wave transaction.
// Head of (c, lane) chunk = c*4 + lane/16; per-head dot = 16-lane butterfly.
// Per-lane softmax state m[4], l[4] (replicated across each 16-lane group).
// ---------------------------------------------------------------------------
__global__ __launch_bounds__(256) void shift_attn(
    const float* __restrict__ cache,   // (2, 16384, 1024): v then k
    float* __restrict__ out,           // d_out
    float* __restrict__ ws) {
  __shared__ float sacc[3][EMBED];
  __shared__ float sm[4][NHEAD];
  __shared__ float sl[4][NHEAD];

  const int wv   = threadIdx.x >> 6;   // wave in block 0..3
  const int lane = threadIdx.x & 63;
  const int grp  = lane >> 4;          // 16-lane group 0..3

  float qf[16];
#pragma unroll
  for (int c = 0; c < 4; ++c) {
    float4 t = *(const float4*)(ws + WS_QKV + c * 256 + lane * 4);
    qf[c * 4] = t.x; qf[c * 4 + 1] = t.y; qf[c * 4 + 2] = t.z; qf[c * 4 + 3] = t.w;
  }

  float m[4] = {-INFINITY, -INFINITY, -INFINITY, -INFINITY};
  float l[4] = {0.f, 0.f, 0.f, 0.f};
  float acc[16];
#pragma unroll
  for (int j = 0; j < 16; ++j) acc[j] = 0.f;

  const float* vin = cache;
  const float* kin = cache + (size_t)CLEN * EMBED;
  float* vout = out + EMBED;
  float* kout = out + EMBED + (size_t)CLEN * EMBED;
  const int t0 = blockIdx.x * 16 + wv * 4;

  for (int it = 0; it < 4; ++it) {
    int t = t0 + it;
    const float* vsrc = (t < CLEN - 1) ? (vin + (size_t)(t + 1) * EMBED)
                                       : (ws + WS_QKV + 2 * EMBED);
    const float* ksrc = (t < CLEN - 1) ? (kin + (size_t)(t + 1) * EMBED)
                                       : (ws + WS_QKV + EMBED);
    float vv[16], kk[16];
#pragma unroll
    for (int c = 0; c < 4; ++c) {
      float4 tv = *(const float4*)(vsrc + c * 256 + lane * 4);
      vv[c * 4] = tv.x; vv[c * 4 + 1] = tv.y; vv[c * 4 + 2] = tv.z; vv[c * 4 + 3] = tv.w;
    }
#pragma unroll
    for (int c = 0; c < 4; ++c) {
      float4 tk = *(const float4*)(ksrc + c * 256 + lane * 4);
      kk[c * 4] = tk.x; kk[c * 4 + 1] = tk.y; kk[c * 4 + 2] = tk.z; kk[c * 4 + 3] = tk.w;
    }
    float* vd = vout + (size_t)t * EMBED;
    float* kd = kout + (size_t)t * EMBED;
#pragma unroll
    for (int c = 0; c < 4; ++c)
      *(float4*)(vd + c * 256 + lane * 4) =
          make_float4(vv[c * 4], vv[c * 4 + 1], vv[c * 4 + 2], vv[c * 4 + 3]);
#pragma unroll
    for (int c = 0; c < 4; ++c)
      *(float4*)(kd + c * 256 + lane * 4) =
          make_float4(kk[c * 4], kk[c * 4 + 1], kk[c * 4 + 2], kk[c * 4 + 3]);

    bool nz = false;
#pragma unroll
    for (int j = 0; j < 16; ++j) nz = nz || (vv[j] != 0.f);

    // per-chunk partial dots, butterfly over the 16-lane group
    float d[4];
#pragma unroll
    for (int c = 0; c < 4; ++c) {
      d[c] = qf[c * 4] * kk[c * 4] + qf[c * 4 + 1] * kk[c * 4 + 1] +
             qf[c * 4 + 2] * kk[c * 4 + 2] + qf[c * 4 + 3] * kk[c * 4 + 3];
    }
#pragma unroll
    for (int msk = 1; msk <= 8; msk <<= 1) {
#pragma unroll
      for (int c = 0; c < 4; ++c) d[c] += __shfl_xor(d[c], msk, 64);
    }

    if (__any((int)nz)) {
#pragma unroll
      for (int c = 0; c < 4; ++c) {
        float s  = d[c] * 0.125f;              // 1/sqrt(64)
        float mn = fmaxf(m[c], s);
        float alpha = __expf(m[c] - mn);       // exp(-inf)=0 on first hit
        float p     = __expf(s - mn);
        l[c] = l[c] * alpha + p;
#pragma unroll
        for (int j = 0; j < 4; ++j)
          acc[c * 4 + j] = acc[c * 4 + j] * alpha + p * vv[c * 4 + j];
        m[c] = mn;
      }
    }
  }

  // intra-block combine: waves 1..3 park partials in LDS, wave 0 merges.
  if (wv > 0) {
#pragma unroll
    for (int c = 0; c < 4; ++c)
      *(float4*)(&sacc[wv - 1][c * 256 + lane * 4]) =
          make_float4(acc[c * 4], acc[c * 4 + 1], acc[c * 4 + 2], acc[c * 4 + 3]);
    if ((lane & 15) == 0) {
#pragma unroll
      for (int c = 0; c < 4; ++c) {
        sm[wv][c * 4 + grp] = m[c];
        sl[wv][c * 4 + grp] = l[c];
      }
    }
  }
  __syncthreads();
  if (wv == 0) {
    for (int w = 1; w < 4; ++w) {
#pragma unroll
      for (int c = 0; c < 4; ++c) {
        float m2 = sm[w][c * 4 + grp];
        float M  = fmaxf(m[c], m2);
        float a1 = (m[c] == -INFINITY) ? 0.f : __expf(m[c] - M);
        float a2 = (m2   == -INFINITY) ? 0.f : __expf(m2 - M);
        l[c] = a1 * l[c] + a2 * sl[w][c * 4 + grp];
        float4 av = *(const float4*)(&sacc[w - 1][c * 256 + lane * 4]);
        acc[c * 4]     = a1 * acc[c * 4]     + a2 * av.x;
        acc[c * 4 + 1] = a1 * acc[c * 4 + 1] + a2 * av.y;
        acc[c * 4 + 2] = a1 * acc[c * 4 + 2] + a2 * av.z;
        acc[c * 4 + 3] = a1 * acc[c * 4 + 3] + a2 * av.w;
        m[c] = M;
      }
    }
    if ((lane & 15) == 0) {
#pragma unroll
      for (int c = 0; c < 4; ++c) {
        ws[WS_PM + blockIdx.x * NHEAD + c * 4 + grp] = m[c];
        ws[WS_PL + blockIdx.x * NHEAD + c * 4 + grp] = l[c];
      }
    }
    float* pa = ws + WS_PACC + (size_t)blockIdx.x * EMBED;
#pragma unroll
    for (int c = 0; c < 4; ++c)
      *(float4*)(pa + c * 256 + lane * 4) =
          make_float4(acc[c * 4], acc[c * 4 + 1], acc[c * 4 + 2], acc[c * 4 + 3]);
  }
}

// C1: 1024 block-partials -> 32 group-partials. 32 blocks x 1024.
__global__ __launch_bounds__(1024) void combine1(float* __restrict__ ws) {
  int g = blockIdx.x, t = threadIdx.x, h = t >> 6;
  int w0 = g * 32;
  float M = -INFINITY;
  for (int w = w0; w < w0 + 32; ++w)
    M = fmaxf(M, ws[WS_PM + w * NHEAD + h]);
  float L = 0.f, a = 0.f;
  for (int w = w0; w < w0 + 32; ++w) {
    float mw = ws[WS_PM + w * NHEAD + h];
    float sc = (mw == -INFINITY) ? 0.f : __expf(mw - M);
    L += sc * ws[WS_PL + w * NHEAD + h];
    a += sc * ws[WS_PACC + (size_t)w * EMBED + t];
  }
  if ((t & 63) == 0) {
    ws[WS_GM + g * NHEAD + h] = M;
    ws[WS_GL + g * NHEAD + h] = L;
  }
  ws[WS_GACC + (size_t)g * EMBED + t] = a;
}

// D (fused combine2 + out-proj partials): 64 blocks x 256.
// Block c covers rows i0 = c*16 .. +15 (all within head i0/64): threads 0..15
// finish the softmax combine for those rows into LDS, then the block does its
// split-K GEMV chunk against Wo.
__global__ __launch_bounds__(256) void out_proj(
    const float* __restrict__ Wo,
    float* __restrict__ ws) {
  __shared__ float svals[16];
  int c = blockIdx.x;
  int i0 = c * 16;
  int h0 = i0 >> 6;
  if (threadIdx.x < 16) {
    int i = i0 + threadIdx.x;
    float M = -INFINITY;
    for (int g = 0; g < 32; ++g)
      M = fmaxf(M, ws[WS_GM + g * NHEAD + h0]);
    float L = 0.f, a = 0.f;
    for (int g = 0; g < 32; ++g) {
      float mg = ws[WS_GM + g * NHEAD + h0];
      float sc = (mg == -INFINITY) ? 0.f : __expf(mg - M);
      L += sc * ws[WS_GL + g * NHEAD + h0];
      a += sc * ws[WS_GACC + (size_t)g * EMBED + i];
    }
    svals[threadIdx.x] = a / L;
  }
  __syncthreads();
  int j = threadIdx.x << 2;
  float4 acc = make_float4(0.f, 0.f, 0.f, 0.f);
  for (int i = 0; i < 16; ++i) {
    float xv = svals[i];
    float4 w = *(const float4*)(Wo + (size_t)(i0 + i) * EMBED + j);
    acc.x += xv * w.x; acc.y += xv * w.y;
    acc.z += xv * w.z; acc.w += xv * w.w;
  }
  *(float4*)(ws + WS_OPART + (size_t)c * EMBED + j) = acc;
}

// D2: reduce 64 partials + bo -> d_out[0:1024]. 1 block x 1024.
__global__ __launch_bounds__(1024) void out_reduce(
    const float* __restrict__ ws, const float* __restrict__ bo,
    float* __restrict__ out) {
  int t = threadIdx.x;
  float s = bo[t];
  const float* p = ws + WS_OPART + t;
  for (int c = 0; c < 64; ++c) s += p[(size_t)c * EMBED];
  out[t] = s;
}

extern "C" void kernel_launch(void* const* d_in, const int* in_sizes, int n_in,
                              void* d_out, int out_size, void* d_ws, size_t ws_size,
                              hipStream_t stream) {
  const float* x     = (const float*)d_in[0];
  const float* cache = (const float*)d_in[1];
  const float* Wv    = (const float*)d_in[2];
  const float* bv    = (const float*)d_in[3];
  const float* Wq    = (const float*)d_in[4];
  const float* bq    = (const float*)d_in[5];
  const float* Wk    = (const float*)d_in[6];
  const float* bk    = (const float*)d_in[7];
  const float* Wo    = (const float*)d_in[8];
  const float* bo    = (const float*)d_in[9];
  float* out = (float*)d_out;
  float* ws  = (float*)d_ws;

  qkv_proj  <<<192, 256, 0, stream>>>(x, Wq, Wk, Wv, ws);
  qkv_reduce<<<12, 256, 0, stream>>>(bq, bk, bv, ws);
  shift_attn<<<1024, 256, 0, stream>>>(cache, out, ws);
  combine1  <<<32, 1024, 0, stream>>>(ws);
  out_proj  <<<64, 256, 0, stream>>>(Wo, ws);
  out_reduce<<<1, 1024, 0, stream>>>(ws, bo, out);
}